// Round 12
// baseline (170.780 us; speedup 1.0000x reference)
//
#include <hip/hip_runtime.h>

// GCN 2-layer encoder: N=50000 nodes, E=800000 edges, 256 -> 128 -> 64.
// Round 12: src-half-ordered edge segments (gathers phase-partitioned so the
// active half-slice fits each XCD's 4MB L2); NBLK 512; fused L1 slice passes.
// GEMMs (async-LDS + fragment-ordered W) unchanged from round 11.

#define IN_C 256
#define HID 128
#define OUTC 64
#define NBLK 512   // blocks for bin_count/bin_scatter

typedef __attribute__((ext_vector_type(8))) short short8;
typedef __attribute__((ext_vector_type(4))) float f32x4;

// ---- async global -> LDS, 16B per lane (dst = wave-uniform base) -----------
__device__ __forceinline__ void gload_lds16(const void* src, void* dst) {
    __builtin_amdgcn_global_load_lds(
        (const __attribute__((address_space(1))) unsigned int*)src,
        (__attribute__((address_space(3))) unsigned int*)dst, 16, 0, 0);
}

// ---- fp32 -> bf16 hi/lo split (RTN, exact residual) ------------------------
__device__ __forceinline__ void bf16split(float f, ushort& h, ushort& l) {
    unsigned u = __float_as_uint(f);
    h = (ushort)(u >> 16);
    float hf = __uint_as_float(u & 0xFFFF0000u);
    unsigned v = __float_as_uint(f - hf);
    l = (ushort)((v + 0x7FFF + ((v >> 16) & 1)) >> 16);
}

// 8x fp32 -> hi/lo bf16 short8, trunc-lo variant
__device__ __forceinline__ void cvt8(float4 f0, float4 f1, short8& hi8, short8& lo8) {
    float ff[8];
    *(float4*)&ff[0] = f0; *(float4*)&ff[4] = f1;
    unsigned* hp = (unsigned*)&hi8;
    unsigned* lp = (unsigned*)&lo8;
    #pragma unroll
    for (int i = 0; i < 4; ++i) {
        unsigned u0 = __float_as_uint(ff[2 * i]), u1 = __float_as_uint(ff[2 * i + 1]);
        unsigned hf0 = u0 & 0xFFFF0000u, hf1 = u1 & 0xFFFF0000u;
        hp[i] = (u0 >> 16) | hf1;
        float r0 = ff[2 * i]     - __uint_as_float(hf0);
        float r1 = ff[2 * i + 1] - __uint_as_float(hf1);
        lp[i] = (__float_as_uint(r0) >> 16) | (__float_as_uint(r1) & 0xFFFF0000u);
    }
}

__device__ __forceinline__ ushort f2bf(float f) {
    unsigned u = __float_as_uint(f);
    return (ushort)((u + 0x7FFF + ((u >> 16) & 1)) >> 16);
}
__device__ __forceinline__ float bf2f(ushort u) {
    return __uint_as_float((unsigned)u << 16);
}

// ---- edge index access (int64 vs int32 detected at runtime) ----------------
__device__ __forceinline__ int edge_at(const void* ei, long long idx, int is32) {
    return is32 ? ((const int*)ei)[idx] : (int)((const long long*)ei)[idx];
}

__global__ void detect_kernel(const unsigned long long* ei, int* flag) {
    if (threadIdx.x == 0 && blockIdx.x == 0) {
        int is32 = 0;
        for (int i = 0; i < 64; ++i)
            if (ei[i] >> 32) { is32 = 1; break; }
        *flag = is32;
    }
}

// ---- W -> MFMA-fragment-ordered hi/lo planes -------------------------------
// wf1: [kidx(8)][nt(8)][pl(2)][lane(64)][8]  (128 KB)
// wf2: [kidx(4)][nt(4)][pl(2)][lane(64)][8]  (32 KB)
__global__ __launch_bounds__(256) void wtrans_kernel(const float* __restrict__ W1,
                                                     const float* __restrict__ W2,
                                                     ushort* __restrict__ wf1,
                                                     ushort* __restrict__ wf2) {
    int id = blockIdx.x * 256 + threadIdx.x;   // 0..10239
    if (id < 8192) {
        int lane = id & 63, r = id >> 6;       // r = kidx*16 + nt*2 + pl
        int pl = r & 1, nt = (r >> 1) & 7, kidx = r >> 4;
        int n = nt * 16 + (lane & 15);
        int kb = kidx * 32 + (lane >> 4) * 8;
        ushort v[8];
        #pragma unroll
        for (int j = 0; j < 8; ++j) {
            ushort h, l; bf16split(W1[(kb + j) * HID + n], h, l);
            v[j] = pl ? l : h;
        }
        *(short8*)&wf1[(size_t)id * 8] = *(short8*)v;
    } else if (id < 10240) {
        int id2 = id - 8192;
        int lane = id2 & 63, r = id2 >> 6;     // r = kidx*8 + nt*2 + pl
        int pl = r & 1, nt = (r >> 1) & 3, kidx = r >> 3;
        int n = nt * 16 + (lane & 15);
        int kb = kidx * 32 + (lane >> 4) * 8;
        ushort v[8];
        #pragma unroll
        for (int j = 0; j < 8; ++j) {
            ushort h, l; bf16split(W2[(kb + j) * OUTC + n], h, l);
            v[j] = pl ? l : h;
        }
        *(short8*)&wf2[(size_t)id2 * 8] = *(short8*)v;
    }
}

// ---- pass 1: per-block histogram over dst buckets (dst>>8) -----------------
__global__ __launch_bounds__(256) void bin_count(const void* ei, const int* __restrict__ flag,
                                                 int* __restrict__ blkcnt, int E, int nb) {
    __shared__ int h[256];
    int t = threadIdx.x;
    h[t] = 0;
    __syncthreads();
    int is32 = *flag;
    int chunk = (E + gridDim.x - 1) / gridDim.x;
    long long s0 = (long long)blockIdx.x * chunk;
    long long s1 = s0 + chunk; if (s1 > E) s1 = E;
    for (long long e = s0 + t; e < s1; e += 256) {
        int d = edge_at(ei, (long long)E + e, is32);
        atomicAdd(&h[d >> 8], 1);
    }
    __syncthreads();
    if (t < nb) blkcnt[t * NBLK + blockIdx.x] = h[t];
}

// ---- pass 2: per-bucket prefix over blocks + bucket-base scan (1 block) ----
__global__ __launch_bounds__(256) void bin_scan(int* __restrict__ blkcnt,
                                                int* __restrict__ bbase, int nb) {
    __shared__ int sh[256];
    int t = threadIdx.x;
    int tot = 0;
    if (t < nb) {
        int4* p = (int4*)&blkcnt[t * NBLK];
        int run = 0;
        for (int i = 0; i < NBLK / 4; ++i) {
            int4 v = p[i]; int4 o;
            o.x = run; run += v.x; o.y = run; run += v.y;
            o.z = run; run += v.z; o.w = run; run += v.w;
            p[i] = o;
        }
        tot = run;
    }
    sh[t] = tot;
    __syncthreads();
    for (int d = 1; d < 256; d <<= 1) {
        int add = (t >= d) ? sh[t - d] : 0;
        __syncthreads();
        sh[t] += add;
        __syncthreads();
    }
    if (t < nb) {
        bbase[t] = sh[t] - tot;              // exclusive
        if (t == nb - 1) bbase[nb] = sh[t];  // = E
    }
}

// ---- pass 3: scatter records into per-(block,bucket) contiguous segments ---
// record = src[17b] | dstlow8 << 17
__global__ __launch_bounds__(256) void bin_scatter(const void* ei, const int* __restrict__ flag,
                                                   const int* __restrict__ blkcnt,
                                                   const int* __restrict__ bbase,
                                                   unsigned* __restrict__ coarse, int E, int nb) {
    __shared__ int cur[256];
    int t = threadIdx.x;
    if (t < nb) cur[t] = bbase[t] + blkcnt[t * NBLK + blockIdx.x];
    __syncthreads();
    int is32 = *flag;
    int chunk = (E + gridDim.x - 1) / gridDim.x;
    long long s0 = (long long)blockIdx.x * chunk;
    long long s1 = s0 + chunk; if (s1 > E) s1 = E;
    for (long long e = s0 + t; e < s1; e += 256) {
        int s = edge_at(ei, e, is32);
        int d = edge_at(ei, (long long)E + e, is32);
        int p = atomicAdd(&cur[d >> 8], 1);
        coarse[p] = (unsigned)s | ((unsigned)(d & 255) << 17);
    }
}

// ---- pass 4: per-bucket sort by (dst, src>=half); emits row_ptr, dis, epk --
// Two sub-bins per dst: edges with src<half come first in each segment, so
// concurrently-running seg_agg waves gather from a 3.2MB (L2-resident)
// half-slice first, then the other half.
__global__ __launch_bounds__(256) void fine_kernel(const unsigned* __restrict__ coarse,
                                                   const int* __restrict__ bbase,
                                                   int* __restrict__ row_ptr,
                                                   float* __restrict__ dis,
                                                   int* __restrict__ epk,
                                                   int N, int nb, int half) {
    __shared__ int h[512], cur[512], ssum[256];
    int b = blockIdx.x, t = threadIdx.x;
    int nb0 = b << 8;
    int e0b = bbase[b], e1b = bbase[b + 1];
    h[t] = 0; h[t + 256] = 0;
    __syncthreads();
    for (int e = e0b + t; e < e1b; e += 256) {
        unsigned r = coarse[e];
        int key = (((r >> 17) & 0xFF) << 1) | ((int)(r & 0x1FFFF) >= half ? 1 : 0);
        atomicAdd(&h[key], 1);
    }
    __syncthreads();
    int v0 = h[2 * t], v1 = h[2 * t + 1];
    int s = v0 + v1;
    ssum[t] = s;
    __syncthreads();
    for (int d = 1; d < 256; d <<= 1) {
        int add = (t >= d) ? ssum[t - d] : 0;
        __syncthreads();
        ssum[t] += add;
        __syncthreads();
    }
    int excl = ssum[t] - s;
    int node = nb0 + t;
    if (node < N) {
        row_ptr[node] = e0b + excl;
        dis[node] = rsqrtf((float)s + 1.0f);          // +1 = self loop
        if (node == N - 1) row_ptr[N] = e0b + ssum[t];  // = E
    }
    cur[2 * t] = e0b + excl;
    cur[2 * t + 1] = e0b + excl + v0;
    __syncthreads();
    for (int e = e0b + t; e < e1b; e += 256) {
        unsigned r = coarse[e];
        int key = (((r >> 17) & 0xFF) << 1) | ((int)(r & 0x1FFFF) >= half ? 1 : 0);
        int p = atomicAdd(&cur[key], 1);
        epk[p] = (int)(r & 0x1FFFF);
    }
}

// ---- zero the sentinel rows (row N of each pre-scaled H buffer) ------------
__global__ void zsent_kernel(ushort* a, ushort* b, ushort* c) {
    int t = threadIdx.x;
    if (t < 64) { a[t] = 0; b[t] = 0; c[t] = 0; }
}

// ---- GEMM1: Hs[2][N+1][64] = (X@W1)*dis ------------------------------------
__global__ __launch_bounds__(256) void gemm1_mfma(const float* __restrict__ X,
                                                  const ushort* __restrict__ wf1,
                                                  const float* __restrict__ dis,
                                                  ushort* __restrict__ HB, int N) {
    __shared__ float xs[64 * 64];   // 16 KB, chunk-swizzled: pos = c ^ (row&7)
    int t = threadIdx.x;
    int lane = t & 63, w = t >> 6;
    int m_off = (w >> 1) * 32, n_off = (w & 1) * 64;
    long long row0 = (long long)blockIdx.x * 64;
    size_t sstride = (size_t)(N + 1) * 64;
    f32x4 acc[2][4] = {};
    for (int k0i = 0; k0i < 4; ++k0i) {
        __syncthreads();
        #pragma unroll
        for (int i = 0; i < 4; ++i) {   // wave stages rows w*16 .. w*16+16
            int lrow = w * 16 + i * 4 + (lane >> 4);
            long long gr = row0 + lrow; if (gr >= N) gr = N - 1;
            int gchunk = (lane & 15) ^ (lrow & 7);
            gload_lds16(X + gr * IN_C + k0i * 64 + gchunk * 4,
                        xs + (w * 16 + i * 4) * 64);
        }
        __syncthreads();
        #pragma unroll
        for (int kk = 0; kk < 2; ++kk) {
            int kidx = k0i * 2 + kk;
            short8 ah[2], al[2], bh[4], bl[4];
            #pragma unroll
            for (int ni = 0; ni < 4; ++ni) {
                int nt = (n_off >> 4) + ni;
                const ushort* bp = wf1 + (size_t)(kidx * 16 + nt * 2) * 512 + lane * 8;
                bh[ni] = *(const short8*)bp;
                bl[ni] = *(const short8*)(bp + 512);
            }
            #pragma unroll
            for (int mi = 0; mi < 2; ++mi) {
                int r = m_off + mi * 16 + (lane & 15);
                int s = r & 7;
                int c0 = kk * 8 + (lane >> 4) * 2;
                float4 f0 = *(float4*)((char*)xs + r * 256 + ((c0 ^ s) * 16));
                float4 f1 = *(float4*)((char*)xs + r * 256 + (((c0 + 1) ^ s) * 16));
                cvt8(f0, f1, ah[mi], al[mi]);
            }
            #pragma unroll
            for (int mi = 0; mi < 2; ++mi)
                #pragma unroll
                for (int ni = 0; ni < 4; ++ni) {
                    acc[mi][ni] = __builtin_amdgcn_mfma_f32_16x16x32_bf16(ah[mi], bh[ni], acc[mi][ni], 0, 0, 0);
                    acc[mi][ni] = __builtin_amdgcn_mfma_f32_16x16x32_bf16(ah[mi], bl[ni], acc[mi][ni], 0, 0, 0);
                    acc[mi][ni] = __builtin_amdgcn_mfma_f32_16x16x32_bf16(al[mi], bh[ni], acc[mi][ni], 0, 0, 0);
                }
        }
    }
    int cr = (lane >> 4) * 4, cc = lane & 15;
    #pragma unroll
    for (int mi = 0; mi < 2; ++mi)
        #pragma unroll
        for (int j = 0; j < 4; ++j) {
            long long gr = row0 + m_off + mi * 16 + cr + j;
            if (gr < N) {
                float dv = dis[gr];
                #pragma unroll
                for (int ni = 0; ni < 4; ++ni) {
                    int col = n_off + ni * 16 + cc;
                    HB[(size_t)(col >> 6) * sstride + gr * 64 + (col & 63)] =
                        f2bf(acc[mi][ni][j] * dv);
                }
            }
        }
}

// ---- GEMM2: Hs2[N+1][64] = A2@W2 * dis (A2 = pre-split swizzled planes) ----
__global__ __launch_bounds__(256) void gemm2_mfma(const ushort* __restrict__ Ah,
                                                  const ushort* __restrict__ Al,
                                                  const ushort* __restrict__ wf2,
                                                  const float* __restrict__ dis,
                                                  ushort* __restrict__ HB, int N) {
    __shared__ ushort ash[64 * 64], asl[64 * 64];   // 8 KB each, swizzled
    int t = threadIdx.x;
    int lane = t & 63, w = t >> 6;
    int m_off = (w >> 1) * 32, n_off = (w & 1) * 32;
    long long row0 = (long long)blockIdx.x * 64;
    f32x4 acc[2][2] = {};
    for (int k0i = 0; k0i < 2; ++k0i) {
        __syncthreads();
        #pragma unroll
        for (int i = 0; i < 2; ++i) {   // wave stages rows w*16 .. w*16+16
            int rbase = w * 16 + i * 8;
            long long gr = row0 + rbase + (lane >> 3);
            size_t so = (size_t)gr * 128 + k0i * 64 + (lane & 7) * 8;
            gload_lds16(Ah + so, ash + rbase * 64);
            gload_lds16(Al + so, asl + rbase * 64);
        }
        __syncthreads();
        #pragma unroll
        for (int kk = 0; kk < 2; ++kk) {
            int kidx = k0i * 2 + kk;
            short8 ah[2], al[2], bh[2], bl[2];
            #pragma unroll
            for (int ni = 0; ni < 2; ++ni) {
                int nt = (n_off >> 4) + ni;
                const ushort* bp = wf2 + (size_t)(kidx * 8 + nt * 2) * 512 + lane * 8;
                bh[ni] = *(const short8*)bp;
                bl[ni] = *(const short8*)(bp + 512);
            }
            #pragma unroll
            for (int mi = 0; mi < 2; ++mi) {
                int r = m_off + mi * 16 + (lane & 15);
                int pos = (kk * 4 + (lane >> 4)) ^ (r & 7);
                ah[mi] = *(short8*)((char*)ash + r * 128 + pos * 16);
                al[mi] = *(short8*)((char*)asl + r * 128 + pos * 16);
            }
            #pragma unroll
            for (int mi = 0; mi < 2; ++mi)
                #pragma unroll
                for (int ni = 0; ni < 2; ++ni) {
                    acc[mi][ni] = __builtin_amdgcn_mfma_f32_16x16x32_bf16(ah[mi], bh[ni], acc[mi][ni], 0, 0, 0);
                    acc[mi][ni] = __builtin_amdgcn_mfma_f32_16x16x32_bf16(ah[mi], bl[ni], acc[mi][ni], 0, 0, 0);
                    acc[mi][ni] = __builtin_amdgcn_mfma_f32_16x16x32_bf16(al[mi], bh[ni], acc[mi][ni], 0, 0, 0);
                }
        }
    }
    int cr = (lane >> 4) * 4, cc = lane & 15;
    #pragma unroll
    for (int mi = 0; mi < 2; ++mi)
        #pragma unroll
        for (int j = 0; j < 4; ++j) {
            long long gr = row0 + m_off + mi * 16 + cr + j;
            if (gr < N) {
                float dv = dis[gr];
                #pragma unroll
                for (int ni = 0; ni < 2; ++ni)
                    HB[gr * OUTC + n_off + ni * 16 + cc] = f2bf(acc[mi][ni][j] * dv);
            }
        }
}

// ---- segment aggregation v7 ------------------------------------------------
// MODE 0: layer 1, BOTH slices in one launch (grid = 2N waves; waves >= N
//         handle slice 1). Epilogue fuses b1+relu+split -> swizzled Ah/Al.
// MODE 1: layer 2 -> out = r + b2 (fp32, stride 64).
template <int MODE>
__global__ __launch_bounds__(256) void seg_agg_v7(const ushort* __restrict__ Hbase,
                                                  const float* __restrict__ dis,
                                                  const int* __restrict__ row_ptr,
                                                  const int* __restrict__ epk,
                                                  const float* __restrict__ bias,
                                                  float* __restrict__ outF,
                                                  ushort* __restrict__ outH,
                                                  ushort* __restrict__ outL,
                                                  int N, size_t sstride) {
    int lane = threadIdx.x & 63;
    long long gw = ((long long)blockIdx.x * blockDim.x + threadIdx.x) >> 6;
    int sl = 0;
    int node = (int)gw;
    if constexpr (MODE == 0) {
        if (node >= N) { sl = 1; node -= N; }
    }
    if (node >= N) return;
    const ushort* hl = Hbase + (size_t)sl * sstride + lane;
    float acc = bf2f(hl[node * 64]);   // self loop (pre-scaled)
    int e0 = row_ptr[node], e1 = row_ptr[node + 1];
    for (int base = e0; base < e1; base += 64) {
        int cnt = min(64, e1 - base);
        int rec = epk[min(base + lane, e1 - 1)];  // one coalesced 4B/lane load
        for (int u0 = 0; u0 < cnt; u0 += 16) {
            float hv[16];
            #pragma unroll
            for (int u = 0; u < 16; ++u) {
                int s = (u0 + u < cnt) ? __builtin_amdgcn_readlane(rec, u0 + u) : N;
                hv[u] = bf2f(hl[s * 64]);
            }
            #pragma unroll
            for (int u = 0; u < 16; ++u)
                acc += hv[u];
        }
    }
    float r = dis[node] * acc;
    if constexpr (MODE == 0) {
        float a2 = fmaxf(r + bias[sl * 64 + lane], 0.f);
        unsigned u = __float_as_uint(a2);
        ushort h = (ushort)(u >> 16);
        float rr = a2 - __uint_as_float(u & 0xFFFF0000u);
        ushort l = (ushort)(__float_as_uint(rr) >> 16);
        int col = sl * 64 + ((((lane >> 3) ^ (node & 7))) << 3) + (lane & 7);
        outH[(size_t)node * 128 + col] = h;
        outL[(size_t)node * 128 + col] = l;
    } else {
        outF[(size_t)node * 64 + lane] = r + bias[lane];
    }
}

extern "C" void kernel_launch(void* const* d_in, const int* in_sizes, int n_in,
                              void* d_out, int out_size, void* d_ws, size_t ws_size,
                              hipStream_t stream) {
    const float* x  = (const float*)d_in[0];
    const void*  ei = d_in[1];
    const float* W1 = (const float*)d_in[2];
    const float* b1 = (const float*)d_in[3];
    const float* W2 = (const float*)d_in[4];
    const float* b2 = (const float*)d_in[5];
    float* out = (float*)d_out;
    int N = in_sizes[0] / IN_C;    // 50000
    int E = in_sizes[1] / 2;       // 800000
    int nb = (N + 255) >> 8;       // 196 dst buckets
    int nblk64 = (N + 63) / 64;    // 782
    int N_pad = nblk64 * 64;       // 50048

    char* ws = (char*)d_ws;
    size_t off = 0;
    auto alloc = [&](size_t bytes) {
        void* p = ws + off;
        off += ((bytes + 255) / 256) * 256;
        return p;
    };
    int*      flag    = (int*)alloc(4);
    int*      blkcnt  = (int*)alloc((size_t)nb * NBLK * 4);
    int*      bbase   = (int*)alloc(((size_t)nb + 1) * 4);
    int*      row_ptr = (int*)alloc(((size_t)N + 1) * 4);
    float*    dis     = (float*)alloc((size_t)N * 4);
    unsigned* coarse  = (unsigned*)alloc((size_t)E * 4);
    int*      epk     = (int*)alloc((size_t)E * 4);
    ushort*   wf1     = (ushort*)alloc(131072);            // 128 KB frag-order
    ushort*   wf2     = (ushort*)alloc(32768);             // 32 KB frag-order
    size_t sstride    = (size_t)(N + 1) * 64;
    ushort*   H1b     = (ushort*)alloc(2 * sstride * 2);   // [2][N+1][64] bf16
    ushort*   Ah      = (ushort*)alloc((size_t)N_pad * 128 * 2);
    ushort*   Al      = (ushort*)alloc((size_t)N_pad * 128 * 2);
    ushort*   H2b     = (ushort*)alloc(sstride * 2);       // [N+1][64] bf16

    detect_kernel<<<1, 64, 0, stream>>>((const unsigned long long*)ei, flag);
    wtrans_kernel<<<40, 256, 0, stream>>>(W1, W2, wf1, wf2);
    bin_count<<<NBLK, 256, 0, stream>>>(ei, flag, blkcnt, E, nb);
    bin_scan<<<1, 256, 0, stream>>>(blkcnt, bbase, nb);
    bin_scatter<<<NBLK, 256, 0, stream>>>(ei, flag, blkcnt, bbase, coarse, E, nb);
    fine_kernel<<<nb, 256, 0, stream>>>(coarse, bbase, row_ptr, dis, epk, N, nb, N / 2);
    zsent_kernel<<<1, 64, 0, stream>>>(H1b + (size_t)N * 64,
                                       H1b + sstride + (size_t)N * 64,
                                       H2b + (size_t)N * 64);
    gemm1_mfma<<<nblk64, 256, 0, stream>>>(x, wf1, dis, H1b, N);

    int agg1_blocks = (int)(((long long)N * 2 * 64 + 255) / 256);
    int agg2_blocks = (int)(((long long)N * 64 + 255) / 256);
    seg_agg_v7<0><<<agg1_blocks, 256, 0, stream>>>(H1b, dis, row_ptr, epk,
                                                   b1, nullptr, Ah, Al, N, sstride);
    gemm2_mfma<<<nblk64, 256, 0, stream>>>(Ah, Al, wf2, dis, H2b, N);
    seg_agg_v7<1><<<agg2_blocks, 256, 0, stream>>>(H2b, dis, row_ptr, epk,
                                                   b2, out, nullptr, nullptr, N, sstride);
}

// Round 13
// 142.067 us; speedup vs baseline: 1.2021x; 1.2021x over previous
//
#include <hip/hip_runtime.h>

// GCN 2-layer encoder: N=50000 nodes, E=800000 edges, 256 -> 128 -> 64.
// Round 13: L1 aggregation gathers dwords (both 64-feature slices per edge,
// halving per-edge instruction count and epk passes); sort pipeline reverted
// to round-9 shape (NBLK=128, 256-bin fine). GEMMs as round 11.

#define IN_C 256
#define HID 128
#define OUTC 64
#define NBLK 128   // blocks for bin_count/bin_scatter

typedef __attribute__((ext_vector_type(8))) short short8;
typedef __attribute__((ext_vector_type(4))) float f32x4;

// ---- async global -> LDS, 16B per lane (dst = wave-uniform base) -----------
__device__ __forceinline__ void gload_lds16(const void* src, void* dst) {
    __builtin_amdgcn_global_load_lds(
        (const __attribute__((address_space(1))) unsigned int*)src,
        (__attribute__((address_space(3))) unsigned int*)dst, 16, 0, 0);
}

// ---- fp32 -> bf16 hi/lo split (RTN, exact residual) ------------------------
__device__ __forceinline__ void bf16split(float f, ushort& h, ushort& l) {
    unsigned u = __float_as_uint(f);
    h = (ushort)(u >> 16);
    float hf = __uint_as_float(u & 0xFFFF0000u);
    unsigned v = __float_as_uint(f - hf);
    l = (ushort)((v + 0x7FFF + ((v >> 16) & 1)) >> 16);
}

// 8x fp32 -> hi/lo bf16 short8, trunc-lo variant
__device__ __forceinline__ void cvt8(float4 f0, float4 f1, short8& hi8, short8& lo8) {
    float ff[8];
    *(float4*)&ff[0] = f0; *(float4*)&ff[4] = f1;
    unsigned* hp = (unsigned*)&hi8;
    unsigned* lp = (unsigned*)&lo8;
    #pragma unroll
    for (int i = 0; i < 4; ++i) {
        unsigned u0 = __float_as_uint(ff[2 * i]), u1 = __float_as_uint(ff[2 * i + 1]);
        unsigned hf0 = u0 & 0xFFFF0000u, hf1 = u1 & 0xFFFF0000u;
        hp[i] = (u0 >> 16) | hf1;
        float r0 = ff[2 * i]     - __uint_as_float(hf0);
        float r1 = ff[2 * i + 1] - __uint_as_float(hf1);
        lp[i] = (__float_as_uint(r0) >> 16) | (__float_as_uint(r1) & 0xFFFF0000u);
    }
}

__device__ __forceinline__ ushort f2bf(float f) {
    unsigned u = __float_as_uint(f);
    return (ushort)((u + 0x7FFF + ((u >> 16) & 1)) >> 16);
}
__device__ __forceinline__ float bf2f(ushort u) {
    return __uint_as_float((unsigned)u << 16);
}

// ---- edge index access (int64 vs int32 detected at runtime) ----------------
__device__ __forceinline__ int edge_at(const void* ei, long long idx, int is32) {
    return is32 ? ((const int*)ei)[idx] : (int)((const long long*)ei)[idx];
}

__global__ void detect_kernel(const unsigned long long* ei, int* flag) {
    if (threadIdx.x == 0 && blockIdx.x == 0) {
        int is32 = 0;
        for (int i = 0; i < 64; ++i)
            if (ei[i] >> 32) { is32 = 1; break; }
        *flag = is32;
    }
}

// ---- W -> MFMA-fragment-ordered hi/lo planes -------------------------------
__global__ __launch_bounds__(256) void wtrans_kernel(const float* __restrict__ W1,
                                                     const float* __restrict__ W2,
                                                     ushort* __restrict__ wf1,
                                                     ushort* __restrict__ wf2) {
    int id = blockIdx.x * 256 + threadIdx.x;   // 0..10239
    if (id < 8192) {
        int lane = id & 63, r = id >> 6;       // r = kidx*16 + nt*2 + pl
        int pl = r & 1, nt = (r >> 1) & 7, kidx = r >> 4;
        int n = nt * 16 + (lane & 15);
        int kb = kidx * 32 + (lane >> 4) * 8;
        ushort v[8];
        #pragma unroll
        for (int j = 0; j < 8; ++j) {
            ushort h, l; bf16split(W1[(kb + j) * HID + n], h, l);
            v[j] = pl ? l : h;
        }
        *(short8*)&wf1[(size_t)id * 8] = *(short8*)v;
    } else if (id < 10240) {
        int id2 = id - 8192;
        int lane = id2 & 63, r = id2 >> 6;     // r = kidx*8 + nt*2 + pl
        int pl = r & 1, nt = (r >> 1) & 3, kidx = r >> 3;
        int n = nt * 16 + (lane & 15);
        int kb = kidx * 32 + (lane >> 4) * 8;
        ushort v[8];
        #pragma unroll
        for (int j = 0; j < 8; ++j) {
            ushort h, l; bf16split(W2[(kb + j) * OUTC + n], h, l);
            v[j] = pl ? l : h;
        }
        *(short8*)&wf2[(size_t)id2 * 8] = *(short8*)v;
    }
}

// ---- pass 1: per-block histogram over dst buckets (dst>>8) -----------------
__global__ __launch_bounds__(256) void bin_count(const void* ei, const int* __restrict__ flag,
                                                 int* __restrict__ blkcnt, int E, int nb) {
    __shared__ int h[256];
    int t = threadIdx.x;
    h[t] = 0;
    __syncthreads();
    int is32 = *flag;
    int chunk = (E + gridDim.x - 1) / gridDim.x;
    long long s0 = (long long)blockIdx.x * chunk;
    long long s1 = s0 + chunk; if (s1 > E) s1 = E;
    for (long long e = s0 + t; e < s1; e += 256) {
        int d = edge_at(ei, (long long)E + e, is32);
        atomicAdd(&h[d >> 8], 1);
    }
    __syncthreads();
    if (t < nb) blkcnt[t * NBLK + blockIdx.x] = h[t];
}

// ---- pass 2: per-bucket prefix over blocks + bucket-base scan (1 block) ----
__global__ __launch_bounds__(256) void bin_scan(int* __restrict__ blkcnt,
                                                int* __restrict__ bbase, int nb) {
    __shared__ int sh[256];
    int t = threadIdx.x;
    int tot = 0;
    if (t < nb) {
        int4* p = (int4*)&blkcnt[t * NBLK];
        int run = 0;
        for (int i = 0; i < NBLK / 4; ++i) {
            int4 v = p[i]; int4 o;
            o.x = run; run += v.x; o.y = run; run += v.y;
            o.z = run; run += v.z; o.w = run; run += v.w;
            p[i] = o;
        }
        tot = run;
    }
    sh[t] = tot;
    __syncthreads();
    for (int d = 1; d < 256; d <<= 1) {
        int add = (t >= d) ? sh[t - d] : 0;
        __syncthreads();
        sh[t] += add;
        __syncthreads();
    }
    if (t < nb) {
        bbase[t] = sh[t] - tot;              // exclusive
        if (t == nb - 1) bbase[nb] = sh[t];  // = E
    }
}

// ---- pass 3: scatter records into per-(block,bucket) contiguous segments ---
// record = src[17b] | dstlow8 << 17
__global__ __launch_bounds__(256) void bin_scatter(const void* ei, const int* __restrict__ flag,
                                                   const int* __restrict__ blkcnt,
                                                   const int* __restrict__ bbase,
                                                   unsigned* __restrict__ coarse, int E, int nb) {
    __shared__ int cur[256];
    int t = threadIdx.x;
    if (t < nb) cur[t] = bbase[t] + blkcnt[t * NBLK + blockIdx.x];
    __syncthreads();
    int is32 = *flag;
    int chunk = (E + gridDim.x - 1) / gridDim.x;
    long long s0 = (long long)blockIdx.x * chunk;
    long long s1 = s0 + chunk; if (s1 > E) s1 = E;
    for (long long e = s0 + t; e < s1; e += 256) {
        int s = edge_at(ei, e, is32);
        int d = edge_at(ei, (long long)E + e, is32);
        int p = atomicAdd(&cur[d >> 8], 1);
        coarse[p] = (unsigned)s | ((unsigned)(d & 255) << 17);
    }
}

// ---- pass 4: per-bucket exact sort by dst; emits row_ptr, dis, epk ---------
__global__ __launch_bounds__(256) void fine_kernel(const unsigned* __restrict__ coarse,
                                                   const int* __restrict__ bbase,
                                                   int* __restrict__ row_ptr,
                                                   float* __restrict__ dis,
                                                   int* __restrict__ epk, int N, int nb) {
    __shared__ int h[256], cur[256], sh[256];
    int b = blockIdx.x, t = threadIdx.x;
    int nb0 = b << 8;
    int e0b = bbase[b], e1b = bbase[b + 1];
    h[t] = 0;
    __syncthreads();
    for (int e = e0b + t; e < e1b; e += 256)
        atomicAdd(&h[(coarse[e] >> 17) & 0xFF], 1);
    __syncthreads();
    int cnt = h[t];
    sh[t] = cnt;
    __syncthreads();
    for (int d = 1; d < 256; d <<= 1) {
        int add = (t >= d) ? sh[t - d] : 0;
        __syncthreads();
        sh[t] += add;
        __syncthreads();
    }
    int excl = sh[t] - cnt;
    int node = nb0 + t;
    if (node < N) {
        row_ptr[node] = e0b + excl;
        dis[node] = rsqrtf((float)cnt + 1.0f);   // +1 = self loop
        if (node == N - 1) row_ptr[N] = e0b + sh[t];  // = E
    }
    cur[t] = e0b + excl;
    __syncthreads();
    for (int e = e0b + t; e < e1b; e += 256) {
        unsigned r = coarse[e];
        int p = atomicAdd(&cur[(r >> 17) & 0xFF], 1);
        epk[p] = (int)(r & 0x1FFFF);
    }
}

// ---- zero the sentinel rows ------------------------------------------------
__global__ void zsent_kernel(ushort* h1, ushort* h2) {
    int t = threadIdx.x;
    if (t < 128) h1[t] = 0;
    if (t < 64)  h2[t] = 0;
}

// ---- GEMM1: Hs[N+1][128] = (X@W1)*dis (row-major bf16) ---------------------
__global__ __launch_bounds__(256) void gemm1_mfma(const float* __restrict__ X,
                                                  const ushort* __restrict__ wf1,
                                                  const float* __restrict__ dis,
                                                  ushort* __restrict__ HB, int N) {
    __shared__ float xs[64 * 64];   // 16 KB, chunk-swizzled: pos = c ^ (row&7)
    int t = threadIdx.x;
    int lane = t & 63, w = t >> 6;
    int m_off = (w >> 1) * 32, n_off = (w & 1) * 64;
    long long row0 = (long long)blockIdx.x * 64;
    f32x4 acc[2][4] = {};
    for (int k0i = 0; k0i < 4; ++k0i) {
        __syncthreads();
        #pragma unroll
        for (int i = 0; i < 4; ++i) {   // wave stages rows w*16 .. w*16+16
            int lrow = w * 16 + i * 4 + (lane >> 4);
            long long gr = row0 + lrow; if (gr >= N) gr = N - 1;
            int gchunk = (lane & 15) ^ (lrow & 7);
            gload_lds16(X + gr * IN_C + k0i * 64 + gchunk * 4,
                        xs + (w * 16 + i * 4) * 64);
        }
        __syncthreads();
        #pragma unroll
        for (int kk = 0; kk < 2; ++kk) {
            int kidx = k0i * 2 + kk;
            short8 ah[2], al[2], bh[4], bl[4];
            #pragma unroll
            for (int ni = 0; ni < 4; ++ni) {
                int nt = (n_off >> 4) + ni;
                const ushort* bp = wf1 + (size_t)(kidx * 16 + nt * 2) * 512 + lane * 8;
                bh[ni] = *(const short8*)bp;
                bl[ni] = *(const short8*)(bp + 512);
            }
            #pragma unroll
            for (int mi = 0; mi < 2; ++mi) {
                int r = m_off + mi * 16 + (lane & 15);
                int s = r & 7;
                int c0 = kk * 8 + (lane >> 4) * 2;
                float4 f0 = *(float4*)((char*)xs + r * 256 + ((c0 ^ s) * 16));
                float4 f1 = *(float4*)((char*)xs + r * 256 + (((c0 + 1) ^ s) * 16));
                cvt8(f0, f1, ah[mi], al[mi]);
            }
            #pragma unroll
            for (int mi = 0; mi < 2; ++mi)
                #pragma unroll
                for (int ni = 0; ni < 4; ++ni) {
                    acc[mi][ni] = __builtin_amdgcn_mfma_f32_16x16x32_bf16(ah[mi], bh[ni], acc[mi][ni], 0, 0, 0);
                    acc[mi][ni] = __builtin_amdgcn_mfma_f32_16x16x32_bf16(ah[mi], bl[ni], acc[mi][ni], 0, 0, 0);
                    acc[mi][ni] = __builtin_amdgcn_mfma_f32_16x16x32_bf16(al[mi], bh[ni], acc[mi][ni], 0, 0, 0);
                }
        }
    }
    int cr = (lane >> 4) * 4, cc = lane & 15;
    #pragma unroll
    for (int mi = 0; mi < 2; ++mi)
        #pragma unroll
        for (int j = 0; j < 4; ++j) {
            long long gr = row0 + m_off + mi * 16 + cr + j;
            if (gr < N) {
                float dv = dis[gr];
                #pragma unroll
                for (int ni = 0; ni < 4; ++ni) {
                    int col = n_off + ni * 16 + cc;
                    HB[gr * HID + col] = f2bf(acc[mi][ni][j] * dv);
                }
            }
        }
}

// ---- GEMM2: Hs2[N+1][64] = A2@W2 * dis (A2 = pre-split swizzled planes) ----
__global__ __launch_bounds__(256) void gemm2_mfma(const ushort* __restrict__ Ah,
                                                  const ushort* __restrict__ Al,
                                                  const ushort* __restrict__ wf2,
                                                  const float* __restrict__ dis,
                                                  ushort* __restrict__ HB, int N) {
    __shared__ ushort ash[64 * 64], asl[64 * 64];   // 8 KB each, swizzled
    int t = threadIdx.x;
    int lane = t & 63, w = t >> 6;
    int m_off = (w >> 1) * 32, n_off = (w & 1) * 32;
    long long row0 = (long long)blockIdx.x * 64;
    f32x4 acc[2][2] = {};
    for (int k0i = 0; k0i < 2; ++k0i) {
        __syncthreads();
        #pragma unroll
        for (int i = 0; i < 2; ++i) {   // wave stages rows w*16 .. w*16+16
            int rbase = w * 16 + i * 8;
            long long gr = row0 + rbase + (lane >> 3);
            size_t so = (size_t)gr * 128 + k0i * 64 + (lane & 7) * 8;
            gload_lds16(Ah + so, ash + rbase * 64);
            gload_lds16(Al + so, asl + rbase * 64);
        }
        __syncthreads();
        #pragma unroll
        for (int kk = 0; kk < 2; ++kk) {
            int kidx = k0i * 2 + kk;
            short8 ah[2], al[2], bh[2], bl[2];
            #pragma unroll
            for (int ni = 0; ni < 2; ++ni) {
                int nt = (n_off >> 4) + ni;
                const ushort* bp = wf2 + (size_t)(kidx * 8 + nt * 2) * 512 + lane * 8;
                bh[ni] = *(const short8*)bp;
                bl[ni] = *(const short8*)(bp + 512);
            }
            #pragma unroll
            for (int mi = 0; mi < 2; ++mi) {
                int r = m_off + mi * 16 + (lane & 15);
                int pos = (kk * 4 + (lane >> 4)) ^ (r & 7);
                ah[mi] = *(short8*)((char*)ash + r * 128 + pos * 16);
                al[mi] = *(short8*)((char*)asl + r * 128 + pos * 16);
            }
            #pragma unroll
            for (int mi = 0; mi < 2; ++mi)
                #pragma unroll
                for (int ni = 0; ni < 2; ++ni) {
                    acc[mi][ni] = __builtin_amdgcn_mfma_f32_16x16x32_bf16(ah[mi], bh[ni], acc[mi][ni], 0, 0, 0);
                    acc[mi][ni] = __builtin_amdgcn_mfma_f32_16x16x32_bf16(ah[mi], bl[ni], acc[mi][ni], 0, 0, 0);
                    acc[mi][ni] = __builtin_amdgcn_mfma_f32_16x16x32_bf16(al[mi], bh[ni], acc[mi][ni], 0, 0, 0);
                }
        }
    }
    int cr = (lane >> 4) * 4, cc = lane & 15;
    #pragma unroll
    for (int mi = 0; mi < 2; ++mi)
        #pragma unroll
        for (int j = 0; j < 4; ++j) {
            long long gr = row0 + m_off + mi * 16 + cr + j;
            if (gr < N) {
                float dv = dis[gr];
                #pragma unroll
                for (int ni = 0; ni < 2; ++ni)
                    HB[gr * OUTC + n_off + ni * 16 + cc] = f2bf(acc[mi][ni][j] * dv);
            }
        }
}

// ---- segment aggregation v8 ------------------------------------------------
// MODE 0: layer 1, row-major H[N+1][128]; each lane gathers a dword (cols
//         2*lane, 2*lane+1) so ONE edge visit covers all 128 features.
//         Epilogue fuses b1+relu+split -> swizzled Ah/Al (uint stores).
// MODE 1: layer 2, H[N+1][64], ushort gathers -> out = r + b2.
template <int MODE>
__global__ __launch_bounds__(256) void seg_agg_v8(const ushort* __restrict__ H,
                                                  const float* __restrict__ dis,
                                                  const int* __restrict__ row_ptr,
                                                  const int* __restrict__ epk,
                                                  const float* __restrict__ bias,
                                                  float* __restrict__ outF,
                                                  ushort* __restrict__ outH,
                                                  ushort* __restrict__ outL,
                                                  int N) {
    int lane = threadIdx.x & 63;
    int node = (int)(((long long)blockIdx.x * blockDim.x + threadIdx.x) >> 6);
    if (node >= N) return;
    int e0 = row_ptr[node], e1 = row_ptr[node + 1];
    if constexpr (MODE == 0) {
        const unsigned* hl = (const unsigned*)H + lane;   // row stride 64 uints
        unsigned v = hl[node * 64];
        float a0 = bf2f((ushort)v), a1 = bf2f((ushort)(v >> 16));
        for (int base = e0; base < e1; base += 64) {
            int cnt = min(64, e1 - base);
            int rec = epk[min(base + lane, e1 - 1)];
            for (int u0 = 0; u0 < cnt; u0 += 16) {
                unsigned hv[16];
                #pragma unroll
                for (int u = 0; u < 16; ++u) {
                    int s = (u0 + u < cnt) ? __builtin_amdgcn_readlane(rec, u0 + u) : N;
                    hv[u] = hl[s * 64];
                }
                #pragma unroll
                for (int u = 0; u < 16; ++u) {
                    a0 += bf2f((ushort)hv[u]);
                    a1 += bf2f((ushort)(hv[u] >> 16));
                }
            }
        }
        float dn = dis[node];
        int c0 = lane * 2;
        float2 bb = *(const float2*)&bias[c0];
        float p0 = fmaxf(dn * a0 + bb.x, 0.f);
        float p1 = fmaxf(dn * a1 + bb.y, 0.f);
        unsigned u0b = __float_as_uint(p0), u1b = __float_as_uint(p1);
        unsigned h0 = u0b >> 16, h1 = u1b >> 16;
        float r0 = p0 - __uint_as_float(u0b & 0xFFFF0000u);
        float r1 = p1 - __uint_as_float(u1b & 0xFFFF0000u);
        unsigned l0 = __float_as_uint(r0) >> 16, l1 = __float_as_uint(r1) >> 16;
        // swizzled store: col pair shares one 8-elem chunk
        int sl = c0 >> 6, e = c0 & 63;
        int ch = ((e >> 3) ^ (node & 7));
        size_t pos = (size_t)node * 128 + sl * 64 + ch * 8 + (e & 7);
        *(unsigned*)&outH[pos] = h0 | (h1 << 16);
        *(unsigned*)&outL[pos] = l0 | (l1 << 16);
    } else {
        const ushort* hl = H + lane;
        float acc = bf2f(hl[node * 64]);
        for (int base = e0; base < e1; base += 64) {
            int cnt = min(64, e1 - base);
            int rec = epk[min(base + lane, e1 - 1)];
            for (int u0 = 0; u0 < cnt; u0 += 16) {
                float hv[16];
                #pragma unroll
                for (int u = 0; u < 16; ++u) {
                    int s = (u0 + u < cnt) ? __builtin_amdgcn_readlane(rec, u0 + u) : N;
                    hv[u] = bf2f(hl[s * 64]);
                }
                #pragma unroll
                for (int u = 0; u < 16; ++u)
                    acc += hv[u];
            }
        }
        outF[(size_t)node * 64 + lane] = dis[node] * acc + bias[lane];
    }
}

extern "C" void kernel_launch(void* const* d_in, const int* in_sizes, int n_in,
                              void* d_out, int out_size, void* d_ws, size_t ws_size,
                              hipStream_t stream) {
    const float* x  = (const float*)d_in[0];
    const void*  ei = d_in[1];
    const float* W1 = (const float*)d_in[2];
    const float* b1 = (const float*)d_in[3];
    const float* W2 = (const float*)d_in[4];
    const float* b2 = (const float*)d_in[5];
    float* out = (float*)d_out;
    int N = in_sizes[0] / IN_C;    // 50000
    int E = in_sizes[1] / 2;       // 800000
    int nb = (N + 255) >> 8;       // 196 dst buckets
    int nblk64 = (N + 63) / 64;    // 782
    int N_pad = nblk64 * 64;       // 50048

    char* ws = (char*)d_ws;
    size_t off = 0;
    auto alloc = [&](size_t bytes) {
        void* p = ws + off;
        off += ((bytes + 255) / 256) * 256;
        return p;
    };
    int*      flag    = (int*)alloc(4);
    int*      blkcnt  = (int*)alloc((size_t)nb * NBLK * 4);
    int*      bbase   = (int*)alloc(((size_t)nb + 1) * 4);
    int*      row_ptr = (int*)alloc(((size_t)N + 1) * 4);
    float*    dis     = (float*)alloc((size_t)N * 4);
    unsigned* coarse  = (unsigned*)alloc((size_t)E * 4);
    int*      epk     = (int*)alloc((size_t)E * 4);
    ushort*   wf1     = (ushort*)alloc(131072);            // 128 KB frag-order
    ushort*   wf2     = (ushort*)alloc(32768);             // 32 KB frag-order
    ushort*   H1b     = (ushort*)alloc(((size_t)N + 1) * HID * 2);  // row-major
    ushort*   Ah      = (ushort*)alloc((size_t)N_pad * 128 * 2);
    ushort*   Al      = (ushort*)alloc((size_t)N_pad * 128 * 2);
    ushort*   H2b     = (ushort*)alloc(((size_t)N + 1) * OUTC * 2);

    detect_kernel<<<1, 64, 0, stream>>>((const unsigned long long*)ei, flag);
    wtrans_kernel<<<40, 256, 0, stream>>>(W1, W2, wf1, wf2);
    bin_count<<<NBLK, 256, 0, stream>>>(ei, flag, blkcnt, E, nb);
    bin_scan<<<1, 256, 0, stream>>>(blkcnt, bbase, nb);
    bin_scatter<<<NBLK, 256, 0, stream>>>(ei, flag, blkcnt, bbase, coarse, E, nb);
    fine_kernel<<<nb, 256, 0, stream>>>(coarse, bbase, row_ptr, dis, epk, N, nb);
    zsent_kernel<<<1, 128, 0, stream>>>(H1b + (size_t)N * HID, H2b + (size_t)N * OUTC);
    gemm1_mfma<<<nblk64, 256, 0, stream>>>(x, wf1, dis, H1b, N);

    int agg_blocks = (int)(((long long)N * 64 + 255) / 256);
    seg_agg_v8<0><<<agg_blocks, 256, 0, stream>>>(H1b, dis, row_ptr, epk,
                                                  b1, nullptr, Ah, Al, N);
    gemm2_mfma<<<nblk64, 256, 0, stream>>>(Ah, Al, wf2, dis, H2b, N);
    seg_agg_v8<1><<<agg_blocks, 256, 0, stream>>>(H2b, dis, row_ptr, epk,
                                                  b2, out, nullptr, nullptr, N);
}

// Round 14
// 140.046 us; speedup vs baseline: 1.2195x; 1.0144x over previous
//
#include <hip/hip_runtime.h>

// GCN 2-layer encoder: N=50000 nodes, E=800000 edges, 256 -> 128 -> 64.
// Round 14: 4-way src-quartile phasing inside each dst segment (gather set
// per phase fits a 4MB XCD L2); detect inlined into edge kernels; zsent
// folded into wtrans; NBLK=256. seg_agg/GEMMs unchanged from round 13.

#define IN_C 256
#define HID 128
#define OUTC 64
#define NBLK 256   // blocks for bin_count/bin_scatter

typedef __attribute__((ext_vector_type(8))) short short8;
typedef __attribute__((ext_vector_type(4))) float f32x4;

// ---- async global -> LDS, 16B per lane (dst = wave-uniform base) -----------
__device__ __forceinline__ void gload_lds16(const void* src, void* dst) {
    __builtin_amdgcn_global_load_lds(
        (const __attribute__((address_space(1))) unsigned int*)src,
        (__attribute__((address_space(3))) unsigned int*)dst, 16, 0, 0);
}

// ---- fp32 -> bf16 hi/lo split (RTN, exact residual) ------------------------
__device__ __forceinline__ void bf16split(float f, ushort& h, ushort& l) {
    unsigned u = __float_as_uint(f);
    h = (ushort)(u >> 16);
    float hf = __uint_as_float(u & 0xFFFF0000u);
    unsigned v = __float_as_uint(f - hf);
    l = (ushort)((v + 0x7FFF + ((v >> 16) & 1)) >> 16);
}

// 8x fp32 -> hi/lo bf16 short8, trunc-lo variant
__device__ __forceinline__ void cvt8(float4 f0, float4 f1, short8& hi8, short8& lo8) {
    float ff[8];
    *(float4*)&ff[0] = f0; *(float4*)&ff[4] = f1;
    unsigned* hp = (unsigned*)&hi8;
    unsigned* lp = (unsigned*)&lo8;
    #pragma unroll
    for (int i = 0; i < 4; ++i) {
        unsigned u0 = __float_as_uint(ff[2 * i]), u1 = __float_as_uint(ff[2 * i + 1]);
        unsigned hf0 = u0 & 0xFFFF0000u, hf1 = u1 & 0xFFFF0000u;
        hp[i] = (u0 >> 16) | hf1;
        float r0 = ff[2 * i]     - __uint_as_float(hf0);
        float r1 = ff[2 * i + 1] - __uint_as_float(hf1);
        lp[i] = (__float_as_uint(r0) >> 16) | (__float_as_uint(r1) & 0xFFFF0000u);
    }
}

__device__ __forceinline__ ushort f2bf(float f) {
    unsigned u = __float_as_uint(f);
    return (ushort)((u + 0x7FFF + ((u >> 16) & 1)) >> 16);
}
__device__ __forceinline__ float bf2f(ushort u) {
    return __uint_as_float((unsigned)u << 16);
}

// ---- edge index access (int64 vs int32, detected per block) ----------------
__device__ __forceinline__ int edge_at(const void* ei, long long idx, int is32) {
    return is32 ? ((const int*)ei)[idx] : (int)((const long long*)ei)[idx];
}

__device__ __forceinline__ int detect32(const void* ei) {
    const unsigned long long* p = (const unsigned long long*)ei;
    int is32 = 0;
    for (int i = 0; i < 64; ++i)
        if (p[i] >> 32) { is32 = 1; break; }
    return is32;
}

// ---- W -> MFMA-fragment-ordered hi/lo planes + sentinel zeroing ------------
__global__ __launch_bounds__(256) void wtrans_kernel(const float* __restrict__ W1,
                                                     const float* __restrict__ W2,
                                                     ushort* __restrict__ wf1,
                                                     ushort* __restrict__ wf2,
                                                     ushort* __restrict__ h1sent,
                                                     ushort* __restrict__ h2sent) {
    int id = blockIdx.x * 256 + threadIdx.x;   // 0..10495
    if (id < 8192) {
        int lane = id & 63, r = id >> 6;       // r = kidx*16 + nt*2 + pl
        int pl = r & 1, nt = (r >> 1) & 7, kidx = r >> 4;
        int n = nt * 16 + (lane & 15);
        int kb = kidx * 32 + (lane >> 4) * 8;
        ushort v[8];
        #pragma unroll
        for (int j = 0; j < 8; ++j) {
            ushort h, l; bf16split(W1[(kb + j) * HID + n], h, l);
            v[j] = pl ? l : h;
        }
        *(short8*)&wf1[(size_t)id * 8] = *(short8*)v;
    } else if (id < 10240) {
        int id2 = id - 8192;
        int lane = id2 & 63, r = id2 >> 6;     // r = kidx*8 + nt*2 + pl
        int pl = r & 1, nt = (r >> 1) & 3, kidx = r >> 3;
        int n = nt * 16 + (lane & 15);
        int kb = kidx * 32 + (lane >> 4) * 8;
        ushort v[8];
        #pragma unroll
        for (int j = 0; j < 8; ++j) {
            ushort h, l; bf16split(W2[(kb + j) * OUTC + n], h, l);
            v[j] = pl ? l : h;
        }
        *(short8*)&wf2[(size_t)id2 * 8] = *(short8*)v;
    } else if (id < 10368) {
        h1sent[id - 10240] = 0;
    } else if (id < 10432) {
        h2sent[id - 10368] = 0;
    }
}

// ---- pass 1: per-block histogram over dst buckets (dst>>8) -----------------
__global__ __launch_bounds__(256) void bin_count(const void* ei,
                                                 int* __restrict__ blkcnt, int E, int nb) {
    __shared__ int h[256];
    __shared__ int s_is32;
    int t = threadIdx.x;
    h[t] = 0;
    if (t == 0) s_is32 = detect32(ei);
    __syncthreads();
    int is32 = s_is32;
    int chunk = (E + gridDim.x - 1) / gridDim.x;
    long long s0 = (long long)blockIdx.x * chunk;
    long long s1 = s0 + chunk; if (s1 > E) s1 = E;
    for (long long e = s0 + t; e < s1; e += 256) {
        int d = edge_at(ei, (long long)E + e, is32);
        atomicAdd(&h[d >> 8], 1);
    }
    __syncthreads();
    if (t < nb) blkcnt[t * NBLK + blockIdx.x] = h[t];
}

// ---- pass 2: per-bucket prefix over blocks + bucket-base scan (1 block) ----
__global__ __launch_bounds__(256) void bin_scan(int* __restrict__ blkcnt,
                                                int* __restrict__ bbase, int nb) {
    __shared__ int sh[256];
    int t = threadIdx.x;
    int tot = 0;
    if (t < nb) {
        int4* p = (int4*)&blkcnt[t * NBLK];
        int run = 0;
        for (int i = 0; i < NBLK / 4; ++i) {
            int4 v = p[i]; int4 o;
            o.x = run; run += v.x; o.y = run; run += v.y;
            o.z = run; run += v.z; o.w = run; run += v.w;
            p[i] = o;
        }
        tot = run;
    }
    sh[t] = tot;
    __syncthreads();
    for (int d = 1; d < 256; d <<= 1) {
        int add = (t >= d) ? sh[t - d] : 0;
        __syncthreads();
        sh[t] += add;
        __syncthreads();
    }
    if (t < nb) {
        bbase[t] = sh[t] - tot;              // exclusive
        if (t == nb - 1) bbase[nb] = sh[t];  // = E
    }
}

// ---- pass 3: scatter records into per-(block,bucket) contiguous segments ---
// record = src[17b] | dstlow8 << 17
__global__ __launch_bounds__(256) void bin_scatter(const void* ei,
                                                   const int* __restrict__ blkcnt,
                                                   const int* __restrict__ bbase,
                                                   unsigned* __restrict__ coarse, int E, int nb) {
    __shared__ int cur[256];
    __shared__ int s_is32;
    int t = threadIdx.x;
    if (t < nb) cur[t] = bbase[t] + blkcnt[t * NBLK + blockIdx.x];
    if (t == 0) s_is32 = detect32(ei);
    __syncthreads();
    int is32 = s_is32;
    int chunk = (E + gridDim.x - 1) / gridDim.x;
    long long s0 = (long long)blockIdx.x * chunk;
    long long s1 = s0 + chunk; if (s1 > E) s1 = E;
    for (long long e = s0 + t; e < s1; e += 256) {
        int s = edge_at(ei, e, is32);
        int d = edge_at(ei, (long long)E + e, is32);
        int p = atomicAdd(&cur[d >> 8], 1);
        coarse[p] = (unsigned)s | ((unsigned)(d & 255) << 17);
    }
}

// ---- pass 4: per-bucket sort by (dst, src-quartile); row_ptr, dis, epk -----
// 4 sub-bins per dst: seg edges ordered by src quartile so concurrent
// seg_agg waves gather from a <=3.2MB (XCD-L2-resident) quarter at a time.
__global__ __launch_bounds__(256) void fine_kernel(const unsigned* __restrict__ coarse,
                                                   const int* __restrict__ bbase,
                                                   int* __restrict__ row_ptr,
                                                   float* __restrict__ dis,
                                                   int* __restrict__ epk,
                                                   int N, int nb, int q1, int q2, int q3) {
    __shared__ int h[1024], cur[1024], ssum[256];
    int b = blockIdx.x, t = threadIdx.x;
    int nb0 = b << 8;
    int e0b = bbase[b], e1b = bbase[b + 1];
    #pragma unroll
    for (int i = 0; i < 4; ++i) h[t + i * 256] = 0;
    __syncthreads();
    for (int e = e0b + t; e < e1b; e += 256) {
        unsigned r = coarse[e];
        int sv = (int)(r & 0x1FFFF);
        int qq = (sv >= q2) ? (sv >= q3 ? 3 : 2) : (sv >= q1 ? 1 : 0);
        atomicAdd(&h[(((r >> 17) & 0xFF) << 2) | qq], 1);
    }
    __syncthreads();
    int v0 = h[4 * t], v1 = h[4 * t + 1], v2 = h[4 * t + 2], v3 = h[4 * t + 3];
    int s = v0 + v1 + v2 + v3;
    ssum[t] = s;
    __syncthreads();
    for (int d = 1; d < 256; d <<= 1) {
        int add = (t >= d) ? ssum[t - d] : 0;
        __syncthreads();
        ssum[t] += add;
        __syncthreads();
    }
    int excl = ssum[t] - s;
    int node = nb0 + t;
    if (node < N) {
        row_ptr[node] = e0b + excl;
        dis[node] = rsqrtf((float)s + 1.0f);            // +1 = self loop
        if (node == N - 1) row_ptr[N] = e0b + ssum[t];  // = E
    }
    cur[4 * t] = e0b + excl;
    cur[4 * t + 1] = e0b + excl + v0;
    cur[4 * t + 2] = e0b + excl + v0 + v1;
    cur[4 * t + 3] = e0b + excl + v0 + v1 + v2;
    __syncthreads();
    for (int e = e0b + t; e < e1b; e += 256) {
        unsigned r = coarse[e];
        int sv = (int)(r & 0x1FFFF);
        int qq = (sv >= q2) ? (sv >= q3 ? 3 : 2) : (sv >= q1 ? 1 : 0);
        int p = atomicAdd(&cur[(((r >> 17) & 0xFF) << 2) | qq], 1);
        epk[p] = sv;
    }
}

// ---- GEMM1: Hs[N+1][128] = (X@W1)*dis (row-major bf16) ---------------------
__global__ __launch_bounds__(256) void gemm1_mfma(const float* __restrict__ X,
                                                  const ushort* __restrict__ wf1,
                                                  const float* __restrict__ dis,
                                                  ushort* __restrict__ HB, int N) {
    __shared__ float xs[64 * 64];   // 16 KB, chunk-swizzled: pos = c ^ (row&7)
    int t = threadIdx.x;
    int lane = t & 63, w = t >> 6;
    int m_off = (w >> 1) * 32, n_off = (w & 1) * 64;
    long long row0 = (long long)blockIdx.x * 64;
    f32x4 acc[2][4] = {};
    for (int k0i = 0; k0i < 4; ++k0i) {
        __syncthreads();
        #pragma unroll
        for (int i = 0; i < 4; ++i) {   // wave stages rows w*16 .. w*16+16
            int lrow = w * 16 + i * 4 + (lane >> 4);
            long long gr = row0 + lrow; if (gr >= N) gr = N - 1;
            int gchunk = (lane & 15) ^ (lrow & 7);
            gload_lds16(X + gr * IN_C + k0i * 64 + gchunk * 4,
                        xs + (w * 16 + i * 4) * 64);
        }
        __syncthreads();
        #pragma unroll
        for (int kk = 0; kk < 2; ++kk) {
            int kidx = k0i * 2 + kk;
            short8 ah[2], al[2], bh[4], bl[4];
            #pragma unroll
            for (int ni = 0; ni < 4; ++ni) {
                int nt = (n_off >> 4) + ni;
                const ushort* bp = wf1 + (size_t)(kidx * 16 + nt * 2) * 512 + lane * 8;
                bh[ni] = *(const short8*)bp;
                bl[ni] = *(const short8*)(bp + 512);
            }
            #pragma unroll
            for (int mi = 0; mi < 2; ++mi) {
                int r = m_off + mi * 16 + (lane & 15);
                int s = r & 7;
                int c0 = kk * 8 + (lane >> 4) * 2;
                float4 f0 = *(float4*)((char*)xs + r * 256 + ((c0 ^ s) * 16));
                float4 f1 = *(float4*)((char*)xs + r * 256 + (((c0 + 1) ^ s) * 16));
                cvt8(f0, f1, ah[mi], al[mi]);
            }
            #pragma unroll
            for (int mi = 0; mi < 2; ++mi)
                #pragma unroll
                for (int ni = 0; ni < 4; ++ni) {
                    acc[mi][ni] = __builtin_amdgcn_mfma_f32_16x16x32_bf16(ah[mi], bh[ni], acc[mi][ni], 0, 0, 0);
                    acc[mi][ni] = __builtin_amdgcn_mfma_f32_16x16x32_bf16(ah[mi], bl[ni], acc[mi][ni], 0, 0, 0);
                    acc[mi][ni] = __builtin_amdgcn_mfma_f32_16x16x32_bf16(al[mi], bh[ni], acc[mi][ni], 0, 0, 0);
                }
        }
    }
    int cr = (lane >> 4) * 4, cc = lane & 15;
    #pragma unroll
    for (int mi = 0; mi < 2; ++mi)
        #pragma unroll
        for (int j = 0; j < 4; ++j) {
            long long gr = row0 + m_off + mi * 16 + cr + j;
            if (gr < N) {
                float dv = dis[gr];
                #pragma unroll
                for (int ni = 0; ni < 4; ++ni) {
                    int col = n_off + ni * 16 + cc;
                    HB[gr * HID + col] = f2bf(acc[mi][ni][j] * dv);
                }
            }
        }
}

// ---- GEMM2: Hs2[N+1][64] = A2@W2 * dis (A2 = pre-split swizzled planes) ----
__global__ __launch_bounds__(256) void gemm2_mfma(const ushort* __restrict__ Ah,
                                                  const ushort* __restrict__ Al,
                                                  const ushort* __restrict__ wf2,
                                                  const float* __restrict__ dis,
                                                  ushort* __restrict__ HB, int N) {
    __shared__ ushort ash[64 * 64], asl[64 * 64];   // 8 KB each, swizzled
    int t = threadIdx.x;
    int lane = t & 63, w = t >> 6;
    int m_off = (w >> 1) * 32, n_off = (w & 1) * 32;
    long long row0 = (long long)blockIdx.x * 64;
    f32x4 acc[2][2] = {};
    for (int k0i = 0; k0i < 2; ++k0i) {
        __syncthreads();
        #pragma unroll
        for (int i = 0; i < 2; ++i) {   // wave stages rows w*16 .. w*16+16
            int rbase = w * 16 + i * 8;
            long long gr = row0 + rbase + (lane >> 3);
            size_t so = (size_t)gr * 128 + k0i * 64 + (lane & 7) * 8;
            gload_lds16(Ah + so, ash + rbase * 64);
            gload_lds16(Al + so, asl + rbase * 64);
        }
        __syncthreads();
        #pragma unroll
        for (int kk = 0; kk < 2; ++kk) {
            int kidx = k0i * 2 + kk;
            short8 ah[2], al[2], bh[2], bl[2];
            #pragma unroll
            for (int ni = 0; ni < 2; ++ni) {
                int nt = (n_off >> 4) + ni;
                const ushort* bp = wf2 + (size_t)(kidx * 8 + nt * 2) * 512 + lane * 8;
                bh[ni] = *(const short8*)bp;
                bl[ni] = *(const short8*)(bp + 512);
            }
            #pragma unroll
            for (int mi = 0; mi < 2; ++mi) {
                int r = m_off + mi * 16 + (lane & 15);
                int pos = (kk * 4 + (lane >> 4)) ^ (r & 7);
                ah[mi] = *(short8*)((char*)ash + r * 128 + pos * 16);
                al[mi] = *(short8*)((char*)asl + r * 128 + pos * 16);
            }
            #pragma unroll
            for (int mi = 0; mi < 2; ++mi)
                #pragma unroll
                for (int ni = 0; ni < 2; ++ni) {
                    acc[mi][ni] = __builtin_amdgcn_mfma_f32_16x16x32_bf16(ah[mi], bh[ni], acc[mi][ni], 0, 0, 0);
                    acc[mi][ni] = __builtin_amdgcn_mfma_f32_16x16x32_bf16(ah[mi], bl[ni], acc[mi][ni], 0, 0, 0);
                    acc[mi][ni] = __builtin_amdgcn_mfma_f32_16x16x32_bf16(al[mi], bh[ni], acc[mi][ni], 0, 0, 0);
                }
        }
    }
    int cr = (lane >> 4) * 4, cc = lane & 15;
    #pragma unroll
    for (int mi = 0; mi < 2; ++mi)
        #pragma unroll
        for (int j = 0; j < 4; ++j) {
            long long gr = row0 + m_off + mi * 16 + cr + j;
            if (gr < N) {
                float dv = dis[gr];
                #pragma unroll
                for (int ni = 0; ni < 2; ++ni)
                    HB[gr * OUTC + n_off + ni * 16 + cc] = f2bf(acc[mi][ni][j] * dv);
            }
        }
}

// ---- segment aggregation v8 (round 13) -------------------------------------
template <int MODE>
__global__ __launch_bounds__(256) void seg_agg_v8(const ushort* __restrict__ H,
                                                  const float* __restrict__ dis,
                                                  const int* __restrict__ row_ptr,
                                                  const int* __restrict__ epk,
                                                  const float* __restrict__ bias,
                                                  float* __restrict__ outF,
                                                  ushort* __restrict__ outH,
                                                  ushort* __restrict__ outL,
                                                  int N) {
    int lane = threadIdx.x & 63;
    int node = (int)(((long long)blockIdx.x * blockDim.x + threadIdx.x) >> 6);
    if (node >= N) return;
    int e0 = row_ptr[node], e1 = row_ptr[node + 1];
    if constexpr (MODE == 0) {
        const unsigned* hl = (const unsigned*)H + lane;   // row stride 64 uints
        unsigned v = hl[node * 64];
        float a0 = bf2f((ushort)v), a1 = bf2f((ushort)(v >> 16));
        for (int base = e0; base < e1; base += 64) {
            int cnt = min(64, e1 - base);
            int rec = epk[min(base + lane, e1 - 1)];
            for (int u0 = 0; u0 < cnt; u0 += 16) {
                unsigned hv[16];
                #pragma unroll
                for (int u = 0; u < 16; ++u) {
                    int s = (u0 + u < cnt) ? __builtin_amdgcn_readlane(rec, u0 + u) : N;
                    hv[u] = hl[s * 64];
                }
                #pragma unroll
                for (int u = 0; u < 16; ++u) {
                    a0 += bf2f((ushort)hv[u]);
                    a1 += bf2f((ushort)(hv[u] >> 16));
                }
            }
        }
        float dn = dis[node];
        int c0 = lane * 2;
        float2 bb = *(const float2*)&bias[c0];
        float p0 = fmaxf(dn * a0 + bb.x, 0.f);
        float p1 = fmaxf(dn * a1 + bb.y, 0.f);
        unsigned u0b = __float_as_uint(p0), u1b = __float_as_uint(p1);
        unsigned h0 = u0b >> 16, h1 = u1b >> 16;
        float r0 = p0 - __uint_as_float(u0b & 0xFFFF0000u);
        float r1 = p1 - __uint_as_float(u1b & 0xFFFF0000u);
        unsigned l0 = __float_as_uint(r0) >> 16, l1 = __float_as_uint(r1) >> 16;
        int sl = c0 >> 6, e = c0 & 63;
        int ch = ((e >> 3) ^ (node & 7));
        size_t pos = (size_t)node * 128 + sl * 64 + ch * 8 + (e & 7);
        *(unsigned*)&outH[pos] = h0 | (h1 << 16);
        *(unsigned*)&outL[pos] = l0 | (l1 << 16);
    } else {
        const ushort* hl = H + lane;
        float acc = bf2f(hl[node * 64]);
        for (int base = e0; base < e1; base += 64) {
            int cnt = min(64, e1 - base);
            int rec = epk[min(base + lane, e1 - 1)];
            for (int u0 = 0; u0 < cnt; u0 += 16) {
                float hv[16];
                #pragma unroll
                for (int u = 0; u < 16; ++u) {
                    int s = (u0 + u < cnt) ? __builtin_amdgcn_readlane(rec, u0 + u) : N;
                    hv[u] = bf2f(hl[s * 64]);
                }
                #pragma unroll
                for (int u = 0; u < 16; ++u)
                    acc += hv[u];
            }
        }
        outF[(size_t)node * 64 + lane] = dis[node] * acc + bias[lane];
    }
}

extern "C" void kernel_launch(void* const* d_in, const int* in_sizes, int n_in,
                              void* d_out, int out_size, void* d_ws, size_t ws_size,
                              hipStream_t stream) {
    const float* x  = (const float*)d_in[0];
    const void*  ei = d_in[1];
    const float* W1 = (const float*)d_in[2];
    const float* b1 = (const float*)d_in[3];
    const float* W2 = (const float*)d_in[4];
    const float* b2 = (const float*)d_in[5];
    float* out = (float*)d_out;
    int N = in_sizes[0] / IN_C;    // 50000
    int E = in_sizes[1] / 2;       // 800000
    int nb = (N + 255) >> 8;       // 196 dst buckets
    int nblk64 = (N + 63) / 64;    // 782
    int N_pad = nblk64 * 64;       // 50048

    char* ws = (char*)d_ws;
    size_t off = 0;
    auto alloc = [&](size_t bytes) {
        void* p = ws + off;
        off += ((bytes + 255) / 256) * 256;
        return p;
    };
    int*      blkcnt  = (int*)alloc((size_t)nb * NBLK * 4);
    int*      bbase   = (int*)alloc(((size_t)nb + 1) * 4);
    int*      row_ptr = (int*)alloc(((size_t)N + 1) * 4);
    float*    dis     = (float*)alloc((size_t)N * 4);
    unsigned* coarse  = (unsigned*)alloc((size_t)E * 4);
    int*      epk     = (int*)alloc((size_t)E * 4);
    ushort*   wf1     = (ushort*)alloc(131072);            // 128 KB frag-order
    ushort*   wf2     = (ushort*)alloc(32768);             // 32 KB frag-order
    ushort*   H1b     = (ushort*)alloc(((size_t)N + 1) * HID * 2);  // row-major
    ushort*   Ah      = (ushort*)alloc((size_t)N_pad * 128 * 2);
    ushort*   Al      = (ushort*)alloc((size_t)N_pad * 128 * 2);
    ushort*   H2b     = (ushort*)alloc(((size_t)N + 1) * OUTC * 2);

    wtrans_kernel<<<41, 256, 0, stream>>>(W1, W2, wf1, wf2,
                                          H1b + (size_t)N * HID,
                                          H2b + (size_t)N * OUTC);
    bin_count<<<NBLK, 256, 0, stream>>>(ei, blkcnt, E, nb);
    bin_scan<<<1, 256, 0, stream>>>(blkcnt, bbase, nb);
    bin_scatter<<<NBLK, 256, 0, stream>>>(ei, blkcnt, bbase, coarse, E, nb);
    fine_kernel<<<nb, 256, 0, stream>>>(coarse, bbase, row_ptr, dis, epk,
                                        N, nb, N / 4, N / 2, (3 * N) / 4);
    gemm1_mfma<<<nblk64, 256, 0, stream>>>(x, wf1, dis, H1b, N);

    int agg_blocks = (int)(((long long)N * 64 + 255) / 256);
    seg_agg_v8<0><<<agg_blocks, 256, 0, stream>>>(H1b, dis, row_ptr, epk,
                                                  b1, nullptr, Ah, Al, N);
    gemm2_mfma<<<nblk64, 256, 0, stream>>>(Ah, Al, wf2, dis, H2b, N);
    seg_agg_v8<1><<<agg_blocks, 256, 0, stream>>>(H2b, dis, row_ptr, epk,
                                                  b2, out, nullptr, nullptr, N);
}